// Round 8
// baseline (94.543 us; speedup 1.0000x reference)
//
#include <hip/hip_runtime.h>

// Embedder: counts = scatter_add(one_hot(tokens)) -> (B, DEPTH) float32
// B=1024, S=200, DEPTH=100000. Output = 409.6 MB -> pure write-BW bound.
//
// Register-accumulated fixup design: all merge work happens BEFORE the
// store stream, in registers.
//   - block = 1/8 row segment (12500 floats). Stage the row's 200
//     (token,value) pairs, compacted to the ~25 that land in this segment
//     (LDS atomic counter).
//   - each thread owns the 13 float4s with f4%256==tid (store mapping
//     f4 = i*256+tid), held in a statically-indexed float4 r[13] (52 VGPR).
//     Scan the compacted list (broadcast ds_read_b64, unroll-4); matches
//     fold into r[j] via fully-unrolled predicated adds. Duplicates just
//     accumulate — no caps, no fallback, no global atomics.
//   - store r[0..12]: 13 coalesced global_store_dwordx4 per thread.
//     ZERO LDS / barriers / RMW in the stream (R7's mistake removed);
//     both barriers precede it and drain only LDS ops (R5's mistake
//     removed); no global zero pass at all (R2/R3's overhead removed).
// LDS = 1.6 KB -> occupancy is VGPR-bound (~5 blocks/CU), blocks retire
// asynchronously so setup phases self-stagger against other blocks'
// store phases.

#define EMB_DEPTH 100000
#define EMB_SEQ   200
#define NSEG      8
#define SEGF      (EMB_DEPTH / NSEG)   // 12500 floats per segment
#define SEGF4     (SEGF / 4)           // 3125 float4 per segment
#define NITER     13                   // ceil(3125 / 256)

__global__ __launch_bounds__(256) void embedder_regacc_kernel(
    const int*   __restrict__ tokens,     // (B, S) int32
    const float* __restrict__ on_values,  // (B, S) float32
    float*       __restrict__ out)        // (B, DEPTH) float32
{
    __shared__ int2 sm[EMB_SEQ];   // compacted (rel_index, value_bits)
    __shared__ int  scount;

    const int tid = threadIdx.x;
    const int b   = blockIdx.x >> 3;       // consecutive blocks ->
    const int seg = blockIdx.x & (NSEG-1); // consecutive memory segments
    const int lo  = seg * SEGF;

    if (tid == 0) scount = 0;
    __syncthreads();

    // Stage + filter: keep only tokens landing in this segment (~25).
    if (tid < EMB_SEQ) {
        const int   t = tokens[(size_t)b * EMB_SEQ + tid];
        const float v = on_values[(size_t)b * EMB_SEQ + tid];
        const unsigned rel = (unsigned)(t - lo);
        if (rel < (unsigned)SEGF) {
            const int pos = atomicAdd(&scount, 1);   // ds_add_rtn_u32
            sm[pos] = make_int2((int)rel, __float_as_int(v));
        }
    }

    // Per-thread accumulators: 13 float4, static indexing only.
    float4 r[NITER];
    #pragma unroll
    for (int i = 0; i < NITER; ++i) r[i] = make_float4(0.f, 0.f, 0.f, 0.f);

    __syncthreads();               // compaction complete (LDS-only drain)
    const int cnt = scount;

    // Scan ~25 entries; broadcast reads; fold matches into registers.
    #pragma unroll 4
    for (int k = 0; k < cnt; ++k) {
        const int2 p   = sm[k];
        const int  rel = p.x;
        const int  f4  = rel >> 2;
        if ((f4 & 255) == tid) {             // exactly one owner thread
            const float v = __int_as_float(p.y);
            const int   j = rel >> 10;       // which of my 13 float4s
            const int   c = rel & 3;         // which component
            #pragma unroll
            for (int i = 0; i < NITER; ++i) {
                if (j == i) {
                    r[i].x += (c == 0) ? v : 0.f;
                    r[i].y += (c == 1) ? v : 0.f;
                    r[i].z += (c == 2) ? v : 0.f;
                    r[i].w += (c == 3) ? v : 0.f;
                }
            }
        }
    }

    // Pure store stream: 13 coalesced dwordx4 per thread, nothing else.
    float4* out4 = reinterpret_cast<float4*>(out + (size_t)b * EMB_DEPTH + lo);
    #pragma unroll
    for (int i = 0; i < NITER; ++i) {
        const int f4 = i * 256 + tid;
        if (f4 < SEGF4) out4[f4] = r[i];   // last iter: tid < 53
    }
}

extern "C" void kernel_launch(void* const* d_in, const int* in_sizes, int n_in,
                              void* d_out, int out_size, void* d_ws, size_t ws_size,
                              hipStream_t stream) {
    const int*   tokens    = (const int*)  d_in[0];
    const float* on_values = (const float*)d_in[1];
    float*       out       = (float*)      d_out;

    const int B = in_sizes[0] / EMB_SEQ;   // 1024
    embedder_regacc_kernel<<<B * NSEG, 256, 0, stream>>>(tokens, on_values, out);
}

// Round 9
// 82.848 us; speedup vs baseline: 1.1412x; 1.1412x over previous
//
#include <hip/hip_runtime.h>

// Embedder: counts = scatter_add(one_hot(tokens)) -> (B, DEPTH) float32
// B=1024, S=200, DEPTH=100000. Output = 409.6 MB -> pure write-BW bound.
//
// Persistent pipelined design: 1024 blocks = exactly 4/CU, resident for the
// whole kernel. Each block owns a 40 KB LDS accumulator (4 x 40 KB = 160 KB/CU)
// and processes 10 units (unit = 40,000 B contiguous output span = 1/10 row).
//
// Per unit: token loads -> zero LDS -> [lgkm barrier] -> ds_add_f32 scatter
// -> [lgkm barrier] -> LDS->global copy (ds_read_b128 + store_dwordx4)
// -> [lgkm barrier] -> next unit.
//
// The barriers are RAW s_barrier with an lgkmcnt(0)-only wait (all cross-wave
// dependencies are LDS: zero->scatter->readback->rezero). __syncthreads would
// emit s_waitcnt vmcnt(0) and drain the global store stream every unit —
// that drain is the phase-serialization tax R2/R3/R5 paid. Here stores stay
// in flight across units; per-unit issue (~2k cy) << per-unit HBM drain
// (~15k cy), so the write stream never starves.

#define EMB_DEPTH 100000
#define EMB_SEQ   200
#define NSEG      10
#define SEGF      (EMB_DEPTH / NSEG)   // 10000 floats = 40,000 B
#define SEGF4     (SEGF / 4)           // 2500 float4
#define NBLOCKS   1024

__global__ __launch_bounds__(256) void embedder_pipe_kernel(
    const int*   __restrict__ tokens,     // (B, S) int32
    const float* __restrict__ on_values,  // (B, S) float32
    float*       __restrict__ out,        // (B, DEPTH) float32
    int nunits)                           // B * NSEG
{
    __shared__ float acc[SEGF];           // 40,000 B
    float4* a4 = reinterpret_cast<float4*>(acc);

    const int tid = threadIdx.x;
    const int blk = blockIdx.x;
    const int upb = nunits / NBLOCKS;     // 10

    for (int it = 0; it < upb; ++it) {
        const int u   = it * NBLOCKS + blk;       // unit: flat 40KB span
        const int row = u / NSEG;
        const int lo  = (u - row * NSEG) * SEGF;  // segment start token id

        // Issue token/value loads now; vmcnt wait lands at first use
        // (the scatter), hidden under zero phase + barrier.
        int   t = 0;
        float v = 0.0f;
        if (tid < EMB_SEQ) {
            t = tokens[(size_t)row * EMB_SEQ + tid];
            v = on_values[(size_t)row * EMB_SEQ + tid];
        }

        // Zero the accumulator: 10 ds_write_b128 per thread.
        #pragma unroll
        for (int k = 0; k < (SEGF4 + 255) / 256; ++k) {
            const int i = k * 256 + tid;
            if (i < SEGF4) a4[i] = make_float4(0.f, 0.f, 0.f, 0.f);
        }
        asm volatile("s_waitcnt lgkmcnt(0)" ::: "memory");
        __builtin_amdgcn_s_barrier();

        // Scatter this row's in-segment tokens (native ds_add_f32).
        if (tid < EMB_SEQ) {
            const unsigned rel = (unsigned)(t - lo);
            if (rel < (unsigned)SEGF) atomicAdd(&acc[rel], v);
        }
        asm volatile("s_waitcnt lgkmcnt(0)" ::: "memory");
        __builtin_amdgcn_s_barrier();

        // Merged write-out: 10 x (ds_read_b128 -> global_store_dwordx4).
        // Global stores are NOT waited on anywhere in this loop.
        float4* o4 = reinterpret_cast<float4*>(out + (size_t)u * SEGF);
        #pragma unroll
        for (int k = 0; k < (SEGF4 + 255) / 256; ++k) {
            const int i = k * 256 + tid;
            if (i < SEGF4) o4[i] = a4[i];
        }
        // LDS reads must finish before the next unit re-zeros acc;
        // lgkm-only again — store stream rides across the barrier.
        asm volatile("s_waitcnt lgkmcnt(0)" ::: "memory");
        __builtin_amdgcn_s_barrier();
    }
}

extern "C" void kernel_launch(void* const* d_in, const int* in_sizes, int n_in,
                              void* d_out, int out_size, void* d_ws, size_t ws_size,
                              hipStream_t stream) {
    const int*   tokens    = (const int*)  d_in[0];
    const float* on_values = (const float*)d_in[1];
    float*       out       = (float*)      d_out;

    const int B = in_sizes[0] / EMB_SEQ;   // 1024
    embedder_pipe_kernel<<<NBLOCKS, 256, 0, stream>>>(
        tokens, on_values, out, B * NSEG);
}